// Round 6
// baseline (940.973 us; speedup 1.0000x reference)
//
#include <hip/hip_runtime.h>
#include <hip/hip_fp16.h>
#include <stdint.h>

typedef __attribute__((ext_vector_type(8))) _Float16 f16x8;
typedef __attribute__((ext_vector_type(4))) float f32x4;

#define MFMA_F16(a, b, c) __builtin_amdgcn_mfma_f32_16x16x32_f16((a), (b), (c), 0, 0, 0)
#define MFMA_BF16(a, b, c) __builtin_amdgcn_mfma_f32_16x16x32_bf16((a), (b), (c), 0, 0, 0)
typedef __attribute__((ext_vector_type(8))) short s16x8;

// ---------- helpers ----------
__device__ __forceinline__ uint32_t pack_hi2(float f0, float f1, float& r0, float& r1) {
  uint32_t b0 = __float_as_uint(f0), b1 = __float_as_uint(f1);
  r0 = f0 - __uint_as_float(b0 & 0xFFFF0000u);
  r1 = f1 - __uint_as_float(b1 & 0xFFFF0000u);
  return (b1 & 0xFFFF0000u) | (b0 >> 16);
}
__device__ __forceinline__ uint32_t pack_lo2(float r0, float r1) {
  return (__float_as_uint(r1) & 0xFFFF0000u) | (__float_as_uint(r0) >> 16);
}
__device__ __forceinline__ uint32_t f16rn(float f) {
  return (uint32_t)__half_as_ushort(__float2half_rn(f));
}
__device__ __forceinline__ float f16tof(uint32_t h) {
  return __half2float(__ushort_as_half((unsigned short)h));
}

// JAX Threefry-2x32, key=(0,42); partitionable: bits = o1^o2, ctr=(0, flat_idx)
__device__ __forceinline__ uint2 threefry2x32_42(uint32_t x0, uint32_t x1) {
  const uint32_t ks0 = 0u, ks1 = 42u, ks2 = 0x1BD11BDAu ^ 42u;
  x0 += ks0; x1 += ks1;
#define TF_R(rot) { x0 += x1; x1 = ((x1 << rot) | (x1 >> (32 - rot))); x1 ^= x0; }
  TF_R(13) TF_R(15) TF_R(26) TF_R(6)   x0 += ks1; x1 += ks2 + 1u;
  TF_R(17) TF_R(29) TF_R(16) TF_R(24)  x0 += ks2; x1 += ks0 + 2u;
  TF_R(13) TF_R(15) TF_R(26) TF_R(6)   x0 += ks0; x1 += ks1 + 3u;
  TF_R(17) TF_R(29) TF_R(16) TF_R(24)  x0 += ks1; x1 += ks2 + 4u;
  TF_R(13) TF_R(15) TF_R(26) TF_R(6)   x0 += ks2; x1 += ks0 + 5u;
#undef TF_R
  return make_uint2(x0, x1);
}

// ============================================================================
// Kernel 1: Y = X @ W (split-3 bf16 MFMA, fp32 accum). Epilogue packs fp16
// pair u32 = (yh<<16)|yl into d_out (scratch until flash overwrites it).
// ============================================================================
__global__ __launch_bounds__(256, 3) void bilin_gemm1(
    const float* __restrict__ X, const float* __restrict__ W,
    uint32_t* __restrict__ Ypk) {
  __shared__ uint16_t sAh[128][40];
  __shared__ uint16_t sAl[128][40];
  __shared__ uint16_t sBh[128][40];
  __shared__ uint16_t sBl[128][40];

  const int t = threadIdx.x;
  const int lane = t & 63;
  const int wv = t >> 6;
  const int wm = wv >> 1, wn = wv & 1;
  const int lc = lane & 15, lg = lane >> 4;
  const int M0 = blockIdx.y * 128;
  const int N0 = blockIdx.x * 128;

  const f32x4 fzero = {0.f, 0.f, 0.f, 0.f};
  f32x4 acc[4][4];
#pragma unroll
  for (int i = 0; i < 4; ++i)
#pragma unroll
    for (int j = 0; j < 4; ++j) acc[i][j] = fzero;

  const int ar = t >> 1;
  const int ak = (t & 1) * 16;
  const int bc = t & 127;
  const int bq = t >> 7;

  const float* aptr = X + (size_t)(M0 + ar) * 1024 + ak;
  const float* bptr = W + (size_t)bq * 16 * 1024 + N0 + bc;

  for (int k0 = 0; k0 < 1024; k0 += 32) {
    {
      const float4* s = (const float4*)(aptr + k0);
#pragma unroll
      for (int q = 0; q < 2; ++q) {
        float4 v0 = s[q * 2 + 0];
        float4 v1 = s[q * 2 + 1];
        float r0, r1, r2, r3, r4, r5, r6, r7;
        uint32_t h0 = pack_hi2(v0.x, v0.y, r0, r1);
        uint32_t h1 = pack_hi2(v0.z, v0.w, r2, r3);
        uint32_t h2 = pack_hi2(v1.x, v1.y, r4, r5);
        uint32_t h3 = pack_hi2(v1.z, v1.w, r6, r7);
        uint32_t l0 = pack_lo2(r0, r1), l1 = pack_lo2(r2, r3);
        uint32_t l2 = pack_lo2(r4, r5), l3 = pack_lo2(r6, r7);
        *(uint4*)&sAh[ar][ak + q * 8] = make_uint4(h0, h1, h2, h3);
        *(uint4*)&sAl[ar][ak + q * 8] = make_uint4(l0, l1, l2, l3);
      }
    }
    {
      float v[16];
#pragma unroll
      for (int i = 0; i < 16; ++i) v[i] = bptr[(size_t)(k0 + i) * 1024];
      float r[16];
      uint32_t h[8], lo[8];
#pragma unroll
      for (int i = 0; i < 8; ++i) h[i] = pack_hi2(v[2 * i], v[2 * i + 1], r[2 * i], r[2 * i + 1]);
#pragma unroll
      for (int i = 0; i < 8; ++i) lo[i] = pack_lo2(r[2 * i], r[2 * i + 1]);
      *(uint4*)&sBh[bc][bq * 16 + 0] = make_uint4(h[0], h[1], h[2], h[3]);
      *(uint4*)&sBh[bc][bq * 16 + 8] = make_uint4(h[4], h[5], h[6], h[7]);
      *(uint4*)&sBl[bc][bq * 16 + 0] = make_uint4(lo[0], lo[1], lo[2], lo[3]);
      *(uint4*)&sBl[bc][bq * 16 + 8] = make_uint4(lo[4], lo[5], lo[6], lo[7]);
    }
    __syncthreads();
    s16x8 ah[4], al[4];
#pragma unroll
    for (int mi = 0; mi < 4; ++mi) {
      ah[mi] = *(const s16x8*)&sAh[wm * 64 + mi * 16 + lc][lg * 8];
      al[mi] = *(const s16x8*)&sAl[wm * 64 + mi * 16 + lc][lg * 8];
    }
#pragma unroll
    for (int ni = 0; ni < 4; ++ni) {
      s16x8 bh = *(const s16x8*)&sBh[wn * 64 + ni * 16 + lc][lg * 8];
      s16x8 bl = *(const s16x8*)&sBl[wn * 64 + ni * 16 + lc][lg * 8];
#pragma unroll
      for (int mi = 0; mi < 4; ++mi) {
        acc[mi][ni] = MFMA_BF16(ah[mi], bh, acc[mi][ni]);
        acc[mi][ni] = MFMA_BF16(ah[mi], bl, acc[mi][ni]);
        acc[mi][ni] = MFMA_BF16(al[mi], bh, acc[mi][ni]);
      }
    }
    __syncthreads();
  }
#pragma unroll
  for (int mi = 0; mi < 4; ++mi)
#pragma unroll
    for (int ni = 0; ni < 4; ++ni)
#pragma unroll
      for (int r = 0; r < 4; ++r) {
        float y = acc[mi][ni][r];
        uint32_t hb = f16rn(y);
        uint32_t lb = f16rn(y - f16tof(hb));
        int row = M0 + wm * 64 + mi * 16 + lg * 4 + r;
        int col = N0 + wn * 64 + ni * 16 + lc;
        Ypk[(size_t)row * 1024 + col] = (hb << 16) | lb;
      }
}

// ============================================================================
// pre_prep: X -> Xh, Xl (fp16 split, row-major) and XhT (fp16 hi, transposed)
// ============================================================================
__global__ __launch_bounds__(256) void pre_prep(const float* __restrict__ X,
    uint16_t* __restrict__ Xh, uint16_t* __restrict__ Xl, uint16_t* __restrict__ XhT) {
  __shared__ uint16_t tile[64][72];
  const int t = threadIdx.x;
  const int b = blockIdx.z;
  const int d0 = blockIdx.x * 64;
  const int k0 = blockIdx.y * 64;
  const int rr = t >> 2;
  const int cq = (t & 3) * 16;
  const float* src = X + (size_t)(b * 2048 + k0 + rr) * 1024 + d0 + cq;
  uint16_t hv[16], lv[16];
#pragma unroll
  for (int q = 0; q < 4; ++q) {
    float4 v = ((const float4*)src)[q];
    float e[4] = {v.x, v.y, v.z, v.w};
#pragma unroll
    for (int j = 0; j < 4; ++j) {
      uint32_t h = f16rn(e[j]);
      hv[q * 4 + j] = (uint16_t)h;
      lv[q * 4 + j] = (uint16_t)f16rn(e[j] - f16tof(h));
      tile[cq + q * 4 + j][rr] = (uint16_t)h;
    }
  }
  size_t rowdst = (size_t)(b * 2048 + k0 + rr) * 1024 + d0 + cq;
  *(uint4*)&Xh[rowdst] = *(const uint4*)&hv[0];
  *(uint4*)&Xh[rowdst + 8] = *(const uint4*)&hv[8];
  *(uint4*)&Xl[rowdst] = *(const uint4*)&lv[0];
  *(uint4*)&Xl[rowdst + 8] = *(const uint4*)&lv[8];
  __syncthreads();
  uint16_t* dst = XhT + (size_t)(b * 1024 + d0 + rr) * 2048 + k0 + cq;
  *(uint4*)dst = *(const uint4*)&tile[rr][cq];
  *(uint4*)(dst + 8) = *(const uint4*)&tile[rr][cq + 8];
}

__global__ __launch_bounds__(256) void maskgen(uint32_t* __restrict__ mw) {
  uint32_t g = blockIdx.x * 256u + threadIdx.x;
  uint2 tf = threefry2x32_42(0u, g);
  uint32_t bits = tf.x ^ tf.y;
  float u = __uint_as_float(0x3F800000u | (bits >> 9)) - 1.0f;
  unsigned long long bal = __ballot(u < 0.9f);
  if ((threadIdx.x & 63) == 0)
    *(uint2*)&mw[g >> 5] = make_uint2((uint32_t)bal, (uint32_t)(bal >> 32));
}

// ============================================================================
// Kernel 2 v3: flash attention, K/V global->register (no LDS staging).
// 512 thr = 8 waves; QBLK=32 (Q hoisted in LDS, fp16 h+l), KB=256
// (wave w owns keys w*32.. in QK, d-slab w*128.. in PV). LDS 150400 B.
// ============================================================================
__global__ __launch_bounds__(512, 2) void bilin_flash3(
    float* __restrict__ YO,
    const uint16_t* __restrict__ Xh, const uint16_t* __restrict__ Xl,
    const uint16_t* __restrict__ XhT, const uint32_t* __restrict__ maskw) {
  __shared__ __align__(16) uint16_t Qh[32][1032];   // 66048
  __shared__ __align__(16) uint16_t Ql[32][1032];   // 66048
  __shared__ __align__(16) uint16_t Pl[32][264];    // 16896
  __shared__ float red[8][32];                      //  1024
  __shared__ float mrow[32], lrow[32], frow[32];    //   384

  const int t = threadIdx.x;
  const int lane = t & 63;
  const int wv = t >> 6;               // 0..7
  const int lc = lane & 15, lg = lane >> 4;

  const int b = blockIdx.x & 7;        // batch -> XCD affinity
  const int q0 = (blockIdx.x >> 3) * 32;

  const uint16_t* Xhb = Xh + (size_t)b * 2048 * 1024;
  const uint16_t* Xlb = Xl + (size_t)b * 2048 * 1024;
  const uint16_t* XhTb = XhT + (size_t)b * 1024 * 2048;
  const uint32_t* Ypk = (const uint32_t*)YO;

  if (t < 32) { mrow[t] = -1e30f; lrow[t] = 0.0f; }

  // ---- hoist Q (32 rows x 1024, fp16 h+l) into LDS, once ----
#pragma unroll 1
  for (int i = 0; i < 16; ++i) {
    int flat = i * 512 + t;            // uint4 index over [32][256]
    int row = flat >> 8;
    int c4 = (flat & 255) * 4;
    uint4 u = *(const uint4*)&Ypk[(size_t)(b * 2048 + q0 + row) * 1024 + c4];
    uint32_t h01 = (u.x >> 16) | (u.y & 0xFFFF0000u);
    uint32_t h23 = (u.z >> 16) | (u.w & 0xFFFF0000u);
    uint32_t l01 = (u.x & 0xFFFFu) | (u.y << 16);
    uint32_t l23 = (u.z & 0xFFFFu) | (u.w << 16);
    *(uint2*)&Qh[row][c4] = make_uint2(h01, h23);
    *(uint2*)&Ql[row][c4] = make_uint2(l01, l23);
  }
  __syncthreads();

  const f32x4 fzero = {0.f, 0.f, 0.f, 0.f};
  f32x4 acc_pv[8][2];
#pragma unroll
  for (int n = 0; n < 8; ++n) { acc_pv[n][0] = fzero; acc_pv[n][1] = fzero; }

  for (int kb = 0; kb < 8; ++kb) {
    const int kbase = kb * 256;

    // ================= QK^T: K global->reg, Q from LDS =================
    f32x4 acc_s[2][2];
#pragma unroll
    for (int i = 0; i < 2; ++i) { acc_s[i][0] = fzero; acc_s[i][1] = fzero; }

    const uint16_t* Kh0 = Xhb + (size_t)(kbase + wv * 32 + lc) * 1024 + lg * 8;
    const uint16_t* Kl0 = Xlb + (size_t)(kbase + wv * 32 + lc) * 1024 + lg * 8;

    f16x8 kh[2][2], kl[2][2];
#pragma unroll
    for (int ni = 0; ni < 2; ++ni) {
      kh[0][ni] = *(const f16x8*)(Kh0 + ni * 16 * 1024);
      kl[0][ni] = *(const f16x8*)(Kl0 + ni * 16 * 1024);
    }
#pragma unroll
    for (int dc = 0; dc < 32; ++dc) {
      const int cb = dc & 1;
      if (dc < 31) {
#pragma unroll
        for (int ni = 0; ni < 2; ++ni) {
          kh[cb ^ 1][ni] = *(const f16x8*)(Kh0 + ni * 16 * 1024 + (dc + 1) * 32);
          kl[cb ^ 1][ni] = *(const f16x8*)(Kl0 + ni * 16 * 1024 + (dc + 1) * 32);
        }
      }
      f16x8 qh0 = *(const f16x8*)&Qh[lc][dc * 32 + lg * 8];
      f16x8 qh1 = *(const f16x8*)&Qh[16 + lc][dc * 32 + lg * 8];
      f16x8 ql0 = *(const f16x8*)&Ql[lc][dc * 32 + lg * 8];
      f16x8 ql1 = *(const f16x8*)&Ql[16 + lc][dc * 32 + lg * 8];
#pragma unroll
      for (int ni = 0; ni < 2; ++ni) {
        acc_s[0][ni] = MFMA_F16(qh0, kh[cb][ni], acc_s[0][ni]);
        acc_s[0][ni] = MFMA_F16(qh0, kl[cb][ni], acc_s[0][ni]);
        acc_s[0][ni] = MFMA_F16(ql0, kh[cb][ni], acc_s[0][ni]);
        acc_s[1][ni] = MFMA_F16(qh1, kh[cb][ni], acc_s[1][ni]);
        acc_s[1][ni] = MFMA_F16(qh1, kl[cb][ni], acc_s[1][ni]);
        acc_s[1][ni] = MFMA_F16(ql1, kh[cb][ni], acc_s[1][ni]);
      }
    }

    // ================= online softmax + fused dropout =================
#pragma unroll
    for (int mi = 0; mi < 2; ++mi)
#pragma unroll
      for (int r = 0; r < 4; ++r) {
        float m = fmaxf(acc_s[mi][0][r], acc_s[mi][1][r]);
        m = fmaxf(m, __shfl_xor(m, 1, 64));
        m = fmaxf(m, __shfl_xor(m, 2, 64));
        m = fmaxf(m, __shfl_xor(m, 4, 64));
        m = fmaxf(m, __shfl_xor(m, 8, 64));
        if (lc == 0) red[wv][mi * 16 + lg * 4 + r] = m;
      }
    __syncthreads();
    if (t < 32) {
      float mk = red[0][t];
#pragma unroll
      for (int w2 = 1; w2 < 8; ++w2) mk = fmaxf(mk, red[w2][t]);
      float mo = mrow[t], mn = fmaxf(mo, mk);
      mrow[t] = mn;
      frow[t] = __expf(mo - mn);
    }
    __syncthreads();
#pragma unroll
    for (int mi = 0; mi < 2; ++mi)
#pragma unroll
      for (int r = 0; r < 4; ++r) {
        const int row = mi * 16 + lg * 4 + r;
        const float mn = mrow[row];
        float p0 = __expf(acc_s[mi][0][r] - mn);
        float p1 = __expf(acc_s[mi][1][r] - mn);
        float s = p0 + p1;
        s += __shfl_xor(s, 1, 64);
        s += __shfl_xor(s, 2, 64);
        s += __shfl_xor(s, 4, 64);
        s += __shfl_xor(s, 8, 64);
        if (lc == 0) red[wv][row] = s;
        uint32_t mwd = maskw[((uint32_t)b * 4194304u + (uint32_t)(q0 + row) * 2048u +
                              (uint32_t)(kbase + wv * 32)) >> 5];
        bool k0 = (mwd >> lc) & 1u;
        bool k1 = (mwd >> (16 + lc)) & 1u;
        Pl[row][wv * 32 + lc] = k0 ? (uint16_t)f16rn(p0) : (uint16_t)0;
        Pl[row][wv * 32 + 16 + lc] = k1 ? (uint16_t)f16rn(p1) : (uint16_t)0;
      }
    __syncthreads();
    if (t < 32) {
      float s = red[0][t];
#pragma unroll
      for (int w2 = 1; w2 < 8; ++w2) s += red[w2][t];
      lrow[t] = lrow[t] * frow[t] + s;
    }

    // ================= PV: V global->reg, P from LDS =================
    {
      float fr[2][4];
#pragma unroll
      for (int mi = 0; mi < 2; ++mi)
#pragma unroll
        for (int r = 0; r < 4; ++r) fr[mi][r] = frow[mi * 16 + lg * 4 + r];
#pragma unroll
      for (int n = 0; n < 8; ++n)
#pragma unroll
        for (int mi = 0; mi < 2; ++mi)
#pragma unroll
          for (int r = 0; r < 4; ++r) acc_pv[n][mi][r] *= fr[mi][r];
    }
    const uint16_t* Vb = XhTb + (size_t)(wv * 128 + lc) * 2048 + kbase + lg * 8;
    f16x8 vfr[2][8];
#pragma unroll
    for (int n = 0; n < 8; ++n) vfr[0][n] = *(const f16x8*)(Vb + (size_t)n * 16 * 2048);
#pragma unroll
    for (int kst = 0; kst < 8; ++kst) {
      const int cb = kst & 1;
      if (kst < 7) {
#pragma unroll
        for (int n = 0; n < 8; ++n)
          vfr[cb ^ 1][n] = *(const f16x8*)(Vb + (size_t)n * 16 * 2048 + (kst + 1) * 32);
      }
      f16x8 pa0 = *(const f16x8*)&Pl[lc][kst * 32 + lg * 8];
      f16x8 pa1 = *(const f16x8*)&Pl[16 + lc][kst * 32 + lg * 8];
#pragma unroll
      for (int n = 0; n < 8; ++n) {
        acc_pv[n][0] = MFMA_F16(pa0, vfr[cb][n], acc_pv[n][0]);
        acc_pv[n][1] = MFMA_F16(pa1, vfr[cb][n], acc_pv[n][1]);
      }
    }
    __syncthreads();  // all PV reads of Pl done before next kb's writes
  }  // kb

  // ================= epilogue: out = acc / (l * 0.9) =================
  float inv[2][4];
#pragma unroll
  for (int mi = 0; mi < 2; ++mi)
#pragma unroll
    for (int r = 0; r < 4; ++r)
      inv[mi][r] = 1.0f / (lrow[mi * 16 + lg * 4 + r] * 0.9f);
  float* outb = YO + (size_t)b * 2048 * 1024;
#pragma unroll
  for (int n = 0; n < 8; ++n)
#pragma unroll
    for (int mi = 0; mi < 2; ++mi)
#pragma unroll
      for (int r = 0; r < 4; ++r)
        outb[(size_t)(q0 + mi * 16 + lg * 4 + r) * 1024 + wv * 128 + n * 16 + lc] =
            acc_pv[n][mi][r] * inv[mi][r];
}

// ============================================================================
// Fallback (no workspace): r5 structure, fp16 dtypes. 512 thr, QBLK=32, KB=128.
// ============================================================================
__global__ __launch_bounds__(512, 4) void bilin_flash2f(
    const float* __restrict__ X, float* __restrict__ YO) {
  __shared__ __align__(16) uint16_t kbuf[2][2][128][40];
  __shared__ __align__(16) uint16_t qbuf[2][2][32][40];
  __shared__ __align__(16) uint16_t Pl[32][136];
  __shared__ float red[8][16];
  __shared__ float mrow[32], lrow[32], frow[32];
  uint16_t* vbase = &kbuf[0][0][0][0];  // vT[2][64][136]

  const int t = threadIdx.x;
  const int lane = t & 63;
  const int wv = t >> 6;
  const int wr = wv >> 2, wc = wv & 3;
  const int lc = lane & 15, lg = lane >> 4;
  const int b = blockIdx.x & 7;
  const int q0 = (blockIdx.x >> 3) * 32;

  const float* Xb = X + (size_t)b * 2048 * 1024;
  const uint32_t* Ypk = (const uint32_t*)YO;

  if (t < 32) { mrow[t] = -1e30f; lrow[t] = 0.0f; }

  const f32x4 fzero = {0.f, 0.f, 0.f, 0.f};
  f32x4 acc_pv[16];
#pragma unroll
  for (int c = 0; c < 16; ++c) acc_pv[c] = fzero;

  const int myrow = wr * 16 + lg * 4;
  const int qsr = t >> 3;
  const int qsc = (t & 7) * 4;
  const int ksk = t >> 2;
  const int ksd = (t & 3) * 8;
  const int vkp = t & 63;
  const int vdg = t >> 6;

  for (int kb = 0; kb < 16; ++kb) {
    const int kbase = kb * 128;
    __syncthreads();

    f32x4 acc_s[2];
    acc_s[0] = fzero; acc_s[1] = fzero;
    uint4 qld;
    float4 kf0, kf1;

    auto load_q = [&](int d0) {
      if (t < 256) qld = *(const uint4*)&Ypk[(size_t)(b * 2048 + q0 + qsr) * 1024 + d0 + qsc];
    };
    auto write_q = [&](int nb) {
      if (t < 256) {
        uint32_t hh0 = (qld.x >> 16) | (qld.y & 0xFFFF0000u);
        uint32_t hh1 = (qld.z >> 16) | (qld.w & 0xFFFF0000u);
        uint32_t ll0 = (qld.x & 0xFFFFu) | (qld.y << 16);
        uint32_t ll1 = (qld.z & 0xFFFFu) | (qld.w << 16);
        *(uint2*)&qbuf[nb][0][qsr][qsc] = make_uint2(hh0, hh1);
        *(uint2*)&qbuf[nb][1][qsr][qsc] = make_uint2(ll0, ll1);
      }
    };
    auto load_k = [&](int d0) {
      const float* s = &Xb[(size_t)(kbase + ksk) * 1024 + d0 + ksd];
      kf0 = ((const float4*)s)[0];
      kf1 = ((const float4*)s)[1];
    };
    auto write_k = [&](int nb) {
      float e[8] = {kf0.x, kf0.y, kf0.z, kf0.w, kf1.x, kf1.y, kf1.z, kf1.w};
      uint32_t h[8], l[8];
#pragma unroll
      for (int j = 0; j < 8; ++j) {
        h[j] = f16rn(e[j]);
        l[j] = f16rn(e[j] - f16tof(h[j]));
      }
      *(uint4*)&kbuf[nb][0][ksk][ksd] =
          make_uint4(h[0] | (h[1] << 16), h[2] | (h[3] << 16), h[4] | (h[5] << 16), h[6] | (h[7] << 16));
      *(uint4*)&kbuf[nb][1][ksk][ksd] =
          make_uint4(l[0] | (l[1] << 16), l[2] | (l[3] << 16), l[4] | (l[5] << 16), l[6] | (l[7] << 16));
    };

    load_q(0); load_k(0);
    write_q(0); write_k(0);
    __syncthreads();
    for (int dc = 0; dc < 32; ++dc) {
      const int cb = dc & 1;
      if (dc < 31) { load_q((dc + 1) * 32); load_k((dc + 1) * 32); }
      f16x8 ah = *(const f16x8*)&qbuf[cb][0][wr * 16 + lc][lg * 8];
      f16x8 al = *(const f16x8*)&qbuf[cb][1][wr * 16 + lc][lg * 8];
#pragma unroll
      for (int ni = 0; ni < 2; ++ni) {
        f16x8 bh = *(const f16x8*)&kbuf[cb][0][wc * 32 + ni * 16 + lc][lg * 8];
        f16x8 bl = *(const f16x8*)&kbuf[cb][1][wc * 32 + ni * 16 + lc][lg * 8];
        acc_s[ni] = MFMA_F16(ah, bh, acc_s[ni]);
        acc_s[ni] = MFMA_F16(ah, bl, acc_s[ni]);
        acc_s[ni] = MFMA_F16(al, bh, acc_s[ni]);
      }
      if (dc < 31) { write_q(cb ^ 1); write_k(cb ^ 1); __syncthreads(); }
    }

#pragma unroll
    for (int r = 0; r < 4; ++r) {
      float m = fmaxf(acc_s[0][r], acc_s[1][r]);
      m = fmaxf(m, __shfl_xor(m, 1, 64));
      m = fmaxf(m, __shfl_xor(m, 2, 64));
      m = fmaxf(m, __shfl_xor(m, 4, 64));
      m = fmaxf(m, __shfl_xor(m, 8, 64));
      if (lc == 0) red[wv][lg * 4 + r] = m;
    }
    __syncthreads();
    if (t < 32) {
      int wrr = t >> 4, rr = t & 15;
      float mk = fmaxf(fmaxf(red[wrr * 4 + 0][rr], red[wrr * 4 + 1][rr]),
                       fmaxf(red[wrr * 4 + 2][rr], red[wrr * 4 + 3][rr]));
      float mo = mrow[t], mn = fmaxf(mo, mk);
      mrow[t] = mn;
      frow[t] = __expf(mo - mn);
    }
    __syncthreads();
#pragma unroll
    for (int r = 0; r < 4; ++r) {
      const int row = myrow + r;
      const float mn = mrow[row];
      float p0 = __expf(acc_s[0][r] - mn);
      float p1 = __expf(acc_s[1][r] - mn);
      float s = p0 + p1;
      s += __shfl_xor(s, 1, 64);
      s += __shfl_xor(s, 2, 64);
      s += __shfl_xor(s, 4, 64);
      s += __shfl_xor(s, 8, 64);
      if (lc == 0) red[wv][lg * 4 + r] = s;
      uint32_t jr = (uint32_t)b * 4194304u + (uint32_t)(q0 + row) * 2048u +
                    (uint32_t)(kbase + wc * 32 + lc);
      uint2 t0 = threefry2x32_42(0u, jr);
      uint2 t1 = threefry2x32_42(0u, jr + 16u);
      bool k0 = (__uint_as_float(0x3F800000u | ((t0.x ^ t0.y) >> 9)) - 1.0f) < 0.9f;
      bool k1 = (__uint_as_float(0x3F800000u | ((t1.x ^ t1.y) >> 9)) - 1.0f) < 0.9f;
      Pl[row][wc * 32 + lc] = k0 ? (uint16_t)f16rn(p0) : (uint16_t)0;
      Pl[row][wc * 32 + 16 + lc] = k1 ? (uint16_t)f16rn(p1) : (uint16_t)0;
    }
    __syncthreads();
    if (t < 32) {
      int wrr = t >> 4, rr = t & 15;
      lrow[t] = lrow[t] * frow[t] + (red[wrr * 4 + 0][rr] + red[wrr * 4 + 1][rr] +
                                     red[wrr * 4 + 2][rr] + red[wrr * 4 + 3][rr]);
    }

    {
      float fr[4];
#pragma unroll
      for (int r = 0; r < 4; ++r) fr[r] = frow[myrow + r];
#pragma unroll
      for (int c = 0; c < 16; ++c)
#pragma unroll
        for (int r = 0; r < 4; ++r) acc_pv[c][r] *= fr[r];
    }
    f16x8 ap[4];
#pragma unroll
    for (int kst = 0; kst < 4; ++kst)
      ap[kst] = *(const f16x8*)&Pl[wr * 16 + lc][kst * 32 + lg * 8];

    float4 vf0, vf1, vf2, vf3;
    auto load_v = [&](int c) {
      const float* s0 = &Xb[(size_t)(kbase + vkp * 2) * 1024 + c * 64 + vdg * 8];
      vf0 = ((const float4*)s0)[0];
      vf1 = ((const float4*)s0)[1];
      vf2 = ((const float4*)(s0 + 1024))[0];
      vf3 = ((const float4*)(s0 + 1024))[1];
    };
    auto write_v = [&](int nb) {
      uint16_t* vt = vbase + nb * (64 * 136);
      float a[8] = {vf0.x, vf0.y, vf0.z, vf0.w, vf1.x, vf1.y, vf1.z, vf1.w};
      float b2[8] = {vf2.x, vf2.y, vf2.z, vf2.w, vf3.x, vf3.y, vf3.z, vf3.w};
#pragma unroll
      for (int j = 0; j < 8; ++j)
        *(uint32_t*)&vt[(vdg * 8 + j) * 136 + vkp * 2] = f16rn(a[j]) | (f16rn(b2[j]) << 16);
    };

    load_v(0); write_v(0);
    __syncthreads();
#pragma unroll
    for (int c = 0; c < 16; ++c) {
      const int cb = c & 1;
      if (c < 15) load_v(c + 1);
      const uint16_t* vt = vbase + cb * (64 * 136);
#pragma unroll
      for (int kst = 0; kst < 4; ++kst) {
        f16x8 bf = *(const f16x8*)&vt[(wc * 16 + lc) * 136 + kst * 32 + lg * 8];
        acc_pv[c] = MFMA_F16(ap[kst], bf, acc_pv[c]);
      }
      if (c < 15) { write_v(cb ^ 1); __syncthreads(); }
    }
  }  // kb

  __syncthreads();
  float inv[4];
#pragma unroll
  for (int r = 0; r < 4; ++r) inv[r] = 1.0f / (lrow[myrow + r] * 0.9f);
  float* outb = YO + (size_t)b * 2048 * 1024;
#pragma unroll
  for (int c = 0; c < 16; ++c)
#pragma unroll
    for (int r = 0; r < 4; ++r)
      outb[(size_t)(q0 + myrow + r) * 1024 + c * 64 + wc * 16 + lc] = acc_pv[c][r] * inv[r];
}

// ============================================================================
extern "C" void kernel_launch(void* const* d_in, const int* in_sizes, int n_in,
                              void* d_out, int out_size, void* d_ws, size_t ws_size,
                              hipStream_t stream) {
  (void)in_sizes; (void)n_in; (void)out_size;
  const float* X = (const float*)d_in[0];
  const float* W = (const float*)d_in[1];
  const bool usews = ws_size >= 104857600ULL;  // XhT(32M)+Xh(32M)+Xl(32M)+mask(4M)

  bilin_gemm1<<<dim3(8, 128), 256, 0, stream>>>(X, W, (uint32_t*)d_out);

  if (usews) {
    uint16_t* XhT = (uint16_t*)d_ws;
    uint16_t* Xh = (uint16_t*)((char*)d_ws + 33554432);
    uint16_t* Xl = (uint16_t*)((char*)d_ws + 67108864);
    uint32_t* mw = (uint32_t*)((char*)d_ws + 100663296);
    pre_prep<<<dim3(16, 32, 8), 256, 0, stream>>>(X, Xh, Xl, XhT);
    maskgen<<<131072, 256, 0, stream>>>(mw);
    bilin_flash3<<<512, 512, 0, stream>>>((float*)d_out, Xh, Xl, XhT, mw);
  } else {
    bilin_flash2f<<<512, 512, 0, stream>>>(X, (float*)d_out);
  }
}